// Round 4
// baseline (597.123 us; speedup 1.0000x reference)
//
#include <hip/hip_runtime.h>

#define N_NODES  100000
#define N_EDGES  1600000
#define N_GRAPHS 512
#define LN_EPS   1e-5f

#define SCAN_CHUNK  1024
#define SCAN_BLOCKS ((N_NODES + SCAN_CHUNK - 1) / SCAN_CHUNK)  // 98

typedef unsigned short u16;
typedef unsigned int   u32;
typedef __attribute__((ext_vector_type(8))) short bf16x8;
typedef __attribute__((ext_vector_type(4))) float f32x4;

__device__ __forceinline__ float b2f(u16 v) {
    u32 u = ((u32)v) << 16;
    return __builtin_bit_cast(float, u);
}
__device__ __forceinline__ u16 f2b(float f) {
    u32 u = __builtin_bit_cast(u32, f);
    u32 r = (u + 0x7fffu + ((u >> 16) & 1u)) >> 16;  // RNE
    return (u16)r;
}

// ---------------- CSR build ----------------

__global__ void count_edges(const int* __restrict__ dst, int* __restrict__ cnt) {
    int e0 = (blockIdx.x * blockDim.x + threadIdx.x) * 4;
    #pragma unroll
    for (int j = 0; j < 4; j++) {
        int e = e0 + j;
        if (e < N_EDGES) atomicAdd(&cnt[dst[e]], 1);
    }
}

__global__ void scan_block_sums(const int* __restrict__ cnt, int* __restrict__ bsum) {
    __shared__ int sh[256];
    int base = blockIdx.x * SCAN_CHUNK;
    int t = threadIdx.x;
    int s = 0;
    for (int j = t; j < SCAN_CHUNK; j += 256) {
        int i = base + j;
        s += (i < N_NODES) ? cnt[i] : 0;
    }
    sh[t] = s; __syncthreads();
    for (int off = 128; off > 0; off >>= 1) {
        if (t < off) sh[t] += sh[t + off];
        __syncthreads();
    }
    if (t == 0) bsum[blockIdx.x] = sh[0];
}

__global__ void scan_bsum_exclusive(int* __restrict__ bsum, int* __restrict__ offsets) {
    __shared__ int sh[128];
    int t = threadIdx.x;
    int v = (t < SCAN_BLOCKS) ? bsum[t] : 0;
    sh[t] = v; __syncthreads();
    for (int off = 1; off < 128; off <<= 1) {
        int add = (t >= off) ? sh[t - off] : 0;
        __syncthreads();
        sh[t] += add;
        __syncthreads();
    }
    if (t < SCAN_BLOCKS) bsum[t] = sh[t] - v;   // exclusive
    if (t == 127) offsets[N_NODES] = sh[127];
}

__global__ void scan_write_offsets(const int* __restrict__ cnt, const int* __restrict__ bsum,
                                   int* __restrict__ offsets) {
    __shared__ int sh[256];
    int b = blockIdx.x, t = threadIdx.x;
    int base = b * SCAN_CHUNK + t * 4;
    int c[4];
    #pragma unroll
    for (int j = 0; j < 4; j++) {
        int i = base + j;
        c[j] = (i < N_NODES) ? cnt[i] : 0;
    }
    int tsum = c[0] + c[1] + c[2] + c[3];
    sh[t] = tsum; __syncthreads();
    for (int off = 1; off < 256; off <<= 1) {
        int add = (t >= off) ? sh[t - off] : 0;
        __syncthreads();
        sh[t] += add;
        __syncthreads();
    }
    int run = sh[t] - tsum + bsum[b];
    #pragma unroll
    for (int j = 0; j < 4; j++) {
        int i = base + j;
        if (i < N_NODES) offsets[i] = run;
        run += c[j];
    }
}

// cursor pre-initialized to offsets (d2d copy); atomic gives ABSOLUTE position.
// atomicExch store: resolves memory-side (L3) -> no 64B partial-line HBM bursts.
__global__ void fill_csr(const int* __restrict__ src, const int* __restrict__ dst,
                         int* __restrict__ cursor, int* __restrict__ csr) {
    int e0 = (blockIdx.x * blockDim.x + threadIdx.x) * 4;
    #pragma unroll
    for (int j = 0; j < 4; j++) {
        int e = e0 + j;
        if (e < N_EDGES) {
            int pos = atomicAdd(&cursor[dst[e]], 1);
            atomicExch(&csr[pos], src[e]);
        }
    }
}

// ---------------- dtype conversions ----------------

__global__ __launch_bounds__(256)
void conv_f32_bf16(const float* __restrict__ in, u16* __restrict__ out, int n4) {
    int i = blockIdx.x * 256 + threadIdx.x;
    if (i < n4) {
        float4 v = ((const float4*)in)[i];
        u32 lo = (u32)f2b(v.x) | ((u32)f2b(v.y) << 16);
        u32 hi = (u32)f2b(v.z) | ((u32)f2b(v.w) << 16);
        ((uint2*)out)[i] = make_uint2(lo, hi);
    }
}

// Wt[c][k] = bf16( k<K1 ? Wl[k][c] : Wr[k-K1][c] ), c in [0,128), k in [0,KC)
__global__ __launch_bounds__(256)
void conv_weights(const float* __restrict__ Wl, const float* __restrict__ Wr,
                  int K1, int KC, u16* __restrict__ Wt) {
    int idx = blockIdx.x * 256 + threadIdx.x;
    if (idx >= 128 * KC) return;
    int c = idx / KC, k = idx % KC;
    float v = (k < K1) ? Wl[k * 128 + c] : Wr[(k - K1) * 128 + c];
    Wt[idx] = f2b(v);
}

// ---------------- mean aggregation (bf16 gather via CSR) ----------------
// 32 lanes per node, 8 nodes per 256-thr block, 4-way edge unroll.

template<int F>
__global__ __launch_bounds__(256)
void aggregate_bf16(const u16* __restrict__ in, const int* __restrict__ offsets,
                    const int* __restrict__ csr, u16* __restrict__ out) {
    int grp = threadIdx.x >> 5;
    int sub = threadIdx.x & 31;
    int n = blockIdx.x * 8 + grp;     // grid 12500 * 8 == N_NODES exactly
    int o0 = offsets[n], o1 = offsets[n + 1];
    int d = o1 - o0;
    float inv = 1.0f / (float)(d > 1 ? d : 1);

    if (F == 128) {
        const uint2* base = (const uint2*)in;      // row stride 32 uint2
        float acc[4][4];
        #pragma unroll
        for (int j = 0; j < 4; j++)
            #pragma unroll
            for (int c = 0; c < 4; c++) acc[j][c] = 0.f;

        int o = o0;
        for (; o + 4 <= o1; o += 4) {
            int s0 = csr[o + 0], s1 = csr[o + 1], s2 = csr[o + 2], s3 = csr[o + 3];
            uint2 v0 = base[(size_t)s0 * 32 + sub];
            uint2 v1 = base[(size_t)s1 * 32 + sub];
            uint2 v2 = base[(size_t)s2 * 32 + sub];
            uint2 v3 = base[(size_t)s3 * 32 + sub];
            acc[0][0] += b2f((u16)(v0.x & 0xffffu)); acc[0][1] += b2f((u16)(v0.x >> 16));
            acc[0][2] += b2f((u16)(v0.y & 0xffffu)); acc[0][3] += b2f((u16)(v0.y >> 16));
            acc[1][0] += b2f((u16)(v1.x & 0xffffu)); acc[1][1] += b2f((u16)(v1.x >> 16));
            acc[1][2] += b2f((u16)(v1.y & 0xffffu)); acc[1][3] += b2f((u16)(v1.y >> 16));
            acc[2][0] += b2f((u16)(v2.x & 0xffffu)); acc[2][1] += b2f((u16)(v2.x >> 16));
            acc[2][2] += b2f((u16)(v2.y & 0xffffu)); acc[2][3] += b2f((u16)(v2.y >> 16));
            acc[3][0] += b2f((u16)(v3.x & 0xffffu)); acc[3][1] += b2f((u16)(v3.x >> 16));
            acc[3][2] += b2f((u16)(v3.y & 0xffffu)); acc[3][3] += b2f((u16)(v3.y >> 16));
        }
        for (; o < o1; o++) {
            int s = csr[o];
            uint2 v = base[(size_t)s * 32 + sub];
            acc[0][0] += b2f((u16)(v.x & 0xffffu)); acc[0][1] += b2f((u16)(v.x >> 16));
            acc[0][2] += b2f((u16)(v.y & 0xffffu)); acc[0][3] += b2f((u16)(v.y >> 16));
        }
        float r0 = ((acc[0][0] + acc[1][0]) + (acc[2][0] + acc[3][0])) * inv;
        float r1 = ((acc[0][1] + acc[1][1]) + (acc[2][1] + acc[3][1])) * inv;
        float r2 = ((acc[0][2] + acc[1][2]) + (acc[2][2] + acc[3][2])) * inv;
        float r3 = ((acc[0][3] + acc[1][3]) + (acc[2][3] + acc[3][3])) * inv;
        uint2 w;
        w.x = (u32)f2b(r0) | ((u32)f2b(r1) << 16);
        w.y = (u32)f2b(r2) | ((u32)f2b(r3) << 16);
        ((uint2*)out)[(size_t)n * 32 + sub] = w;
    } else {
        const u32* base = (const u32*)in;          // row stride 32 u32
        float acc[4][2];
        #pragma unroll
        for (int j = 0; j < 4; j++) { acc[j][0] = 0.f; acc[j][1] = 0.f; }

        int o = o0;
        for (; o + 4 <= o1; o += 4) {
            int s0 = csr[o + 0], s1 = csr[o + 1], s2 = csr[o + 2], s3 = csr[o + 3];
            u32 v0 = base[(size_t)s0 * 32 + sub];
            u32 v1 = base[(size_t)s1 * 32 + sub];
            u32 v2 = base[(size_t)s2 * 32 + sub];
            u32 v3 = base[(size_t)s3 * 32 + sub];
            acc[0][0] += b2f((u16)(v0 & 0xffffu)); acc[0][1] += b2f((u16)(v0 >> 16));
            acc[1][0] += b2f((u16)(v1 & 0xffffu)); acc[1][1] += b2f((u16)(v1 >> 16));
            acc[2][0] += b2f((u16)(v2 & 0xffffu)); acc[2][1] += b2f((u16)(v2 >> 16));
            acc[3][0] += b2f((u16)(v3 & 0xffffu)); acc[3][1] += b2f((u16)(v3 >> 16));
        }
        for (; o < o1; o++) {
            int s = csr[o];
            u32 v = base[(size_t)s * 32 + sub];
            acc[0][0] += b2f((u16)(v & 0xffffu)); acc[0][1] += b2f((u16)(v >> 16));
        }
        float r0 = ((acc[0][0] + acc[1][0]) + (acc[2][0] + acc[3][0])) * inv;
        float r1 = ((acc[0][1] + acc[1][1]) + (acc[2][1] + acc[3][1])) * inv;
        ((u32*)out)[(size_t)n * 32 + sub] = (u32)f2b(r0) | ((u32)f2b(r1) << 16);
    }
}

// ---------------- fused dual GEMM via MFMA ----------------

template<int KHALF>
__global__ __launch_bounds__(256)
void gemm_mfma(const u16* __restrict__ A1, const u16* __restrict__ A2,
               const u16* __restrict__ Wt, const float* __restrict__ bias,
               u16* __restrict__ out) {
    constexpr int KC  = 2 * KHALF;
    constexpr int NKS = KC / 32;

    int t = threadIdx.x;
    int lane = t & 63, w = t >> 6;
    int l15 = lane & 15, l4 = lane >> 4;
    int mbase = blockIdx.x * 64;

    bf16x8 bfr[2][NKS];
    #pragma unroll
    for (int ct = 0; ct < 2; ct++)
        #pragma unroll
        for (int ks = 0; ks < NKS; ks++) {
            int row = w * 32 + ct * 16 + l15;          // output col
            int kb  = ks * 32 + l4 * 8;
            bfr[ct][ks] = *reinterpret_cast<const bf16x8*>(Wt + row * KC + kb);
        }

    f32x4 acc[4][2];
    #pragma unroll
    for (int i = 0; i < 4; i++)
        #pragma unroll
        for (int j = 0; j < 2; j++)
            acc[i][j] = (f32x4){0.f, 0.f, 0.f, 0.f};

    const bf16x8 zfr = {0, 0, 0, 0, 0, 0, 0, 0};

    #pragma unroll
    for (int ks = 0; ks < NKS; ks++) {
        const u16* Ab = (ks < NKS / 2) ? A1 : A2;
        int kb = (ks < NKS / 2) ? (ks * 32 + l4 * 8) : ((ks - NKS / 2) * 32 + l4 * 8);
        bf16x8 afr[4];
        #pragma unroll
        for (int rt = 0; rt < 4; rt++) {
            int row = mbase + rt * 16 + l15;
            afr[rt] = (row < N_NODES)
                ? *reinterpret_cast<const bf16x8*>(Ab + (size_t)row * KHALF + kb)
                : zfr;
        }
        #pragma unroll
        for (int rt = 0; rt < 4; rt++)
            #pragma unroll
            for (int ct = 0; ct < 2; ct++)
                acc[rt][ct] = __builtin_amdgcn_mfma_f32_16x16x32_bf16(
                    afr[rt], bfr[ct][ks], acc[rt][ct], 0, 0, 0);
    }

    // epilogue: bias + relu, store bf16. C/D: col=lane&15, row=(lane>>4)*4+reg
    #pragma unroll
    for (int ct = 0; ct < 2; ct++) {
        int col = w * 32 + ct * 16 + l15;
        float bv = bias[col];
        #pragma unroll
        for (int rt = 0; rt < 4; rt++) {
            #pragma unroll
            for (int j = 0; j < 4; j++) {
                int row = mbase + rt * 16 + l4 * 4 + j;
                if (row < N_NODES) {
                    float v = fmaxf(acc[rt][ct][j] + bv, 0.f);
                    out[(size_t)row * 128 + col] = f2b(v);
                }
            }
        }
    }
}

// ---------------- pool + LayerNorm + decode ----------------

__global__ __launch_bounds__(128)
void pool_ln_decode(const u16* __restrict__ h, const int* __restrict__ batch,
                    const float* __restrict__ ln_g, const float* __restrict__ ln_b,
                    const float* __restrict__ Wd, const float* __restrict__ bd,
                    float* __restrict__ out) {
    __shared__ float red[128];
    __shared__ int bounds[2];
    int g = blockIdx.x, c = threadIdx.x;
    if (c < 2) {
        int target = g + c;
        int lo = 0, hi = N_NODES;
        while (lo < hi) {
            int mid = (lo + hi) >> 1;
            if (batch[mid] < target) lo = mid + 1; else hi = mid;
        }
        bounds[c] = lo;
    }
    __syncthreads();
    int start = bounds[0], end = bounds[1];

    float s = 0.f;
    for (int r = start; r < end; r++) s += b2f(h[(size_t)r * 128 + c]);

    red[c] = s; __syncthreads();
    for (int off = 64; off > 0; off >>= 1) {
        if (c < off) red[c] += red[c + off];
        __syncthreads();
    }
    float mu = red[0] * (1.0f / 128.f);
    __syncthreads();

    float d = s - mu;
    red[c] = d * d; __syncthreads();
    for (int off = 64; off > 0; off >>= 1) {
        if (c < off) red[c] += red[c + off];
        __syncthreads();
    }
    float var = red[0] * (1.0f / 128.f);
    __syncthreads();

    float gn = d * rsqrtf(var + LN_EPS) * ln_g[c] + ln_b[c];

    red[c] = gn * Wd[c * 2 + 0]; __syncthreads();
    for (int off = 64; off > 0; off >>= 1) {
        if (c < off) red[c] += red[c + off];
        __syncthreads();
    }
    float o0 = red[0];
    __syncthreads();

    red[c] = gn * Wd[c * 2 + 1]; __syncthreads();
    for (int off = 64; off > 0; off >>= 1) {
        if (c < off) red[c] += red[c + off];
        __syncthreads();
    }
    if (c == 0) {
        out[g * 2 + 0] = o0 + bd[0];
        out[g * 2 + 1] = red[0] + bd[1];
    }
}

// ---------------- host launcher ----------------

extern "C" void kernel_launch(void* const* d_in, const int* in_sizes, int n_in,
                              void* d_out, int out_size, void* d_ws, size_t ws_size,
                              hipStream_t stream) {
    (void)in_sizes; (void)n_in; (void)out_size; (void)ws_size;

    const float* x     = (const float*)d_in[0];
    const int*   ei    = (const int*)d_in[1];
    const int*   batch = (const int*)d_in[2];
    const float* Wl0 = (const float*)d_in[3];
    const float* bl0 = (const float*)d_in[4];
    const float* Wr0 = (const float*)d_in[5];
    const float* Wl1 = (const float*)d_in[6];
    const float* bl1 = (const float*)d_in[7];
    const float* Wr1 = (const float*)d_in[8];
    const float* Wl2 = (const float*)d_in[9];
    const float* bl2 = (const float*)d_in[10];
    const float* Wr2 = (const float*)d_in[11];
    const float* ln_g = (const float*)d_in[12];
    const float* ln_b = (const float*)d_in[13];
    const float* Wd  = (const float*)d_in[14];
    const float* bd  = (const float*)d_in[15];
    float* out = (float*)d_out;

    const int* src = ei;
    const int* dst = ei + N_EDGES;

    // workspace layout (bytes)
    char* ws = (char*)d_ws;
    int* csr     = (int*)(ws + 0);            //  6,400,000
    int* offsets = (int*)(ws + 6400000);      //    400,004
    int* cnt     = (int*)(ws + 6800128);      //    400,000
    int* cursor  = (int*)(ws + 7200128);      //    400,000
    int* bsum    = (int*)(ws + 7600128);      //        512
    u16* x16     = (u16*)(ws + 7600640);      // 12,800,000
    u16* aggbuf  = (u16*)(ws + 20400640);     // 25,600,000
    u16* bufB    = (u16*)(ws + 46000640);     // 25,600,000
    u16* bufC    = (u16*)(ws + 71600640);     // 25,600,000
    u16* Wt0     = (u16*)(ws + 97200640);     //     32,768
    u16* Wt1     = (u16*)(ws + 97233408);     //     65,536
    u16* Wt2     = (u16*)(ws + 97298944);     //     65,536
    // total: 97,364,480 bytes

    hipMemsetAsync(cnt, 0, N_NODES * sizeof(int), stream);

    count_edges<<<(N_EDGES / 4 + 255) / 256, 256, 0, stream>>>(dst, cnt);
    scan_block_sums<<<SCAN_BLOCKS, 256, 0, stream>>>(cnt, bsum);
    scan_bsum_exclusive<<<1, 128, 0, stream>>>(bsum, offsets);
    scan_write_offsets<<<SCAN_BLOCKS, 256, 0, stream>>>(cnt, bsum, offsets);
    // cursor starts at each node's base offset -> fill atomics give absolute pos
    hipMemcpyAsync(cursor, offsets, N_NODES * sizeof(int), hipMemcpyDeviceToDevice, stream);
    fill_csr<<<(N_EDGES / 4 + 255) / 256, 256, 0, stream>>>(src, dst, cursor, csr);

    // conversions
    conv_f32_bf16<<<(N_NODES * 64 / 4 + 255) / 256, 256, 0, stream>>>(x, x16, N_NODES * 64 / 4);
    conv_weights<<<(128 * 128 + 255) / 256, 256, 0, stream>>>(Wl0, Wr0, 64, 128, Wt0);
    conv_weights<<<(128 * 256 + 255) / 256, 256, 0, stream>>>(Wl1, Wr1, 128, 256, Wt1);
    conv_weights<<<(128 * 256 + 255) / 256, 256, 0, stream>>>(Wl2, Wr2, 128, 256, Wt2);

    const int aggGrid  = N_NODES / 8;               // 12500 (exact)
    const int gemmGrid = (N_NODES + 63) / 64;       // 1563

    // layer 0
    aggregate_bf16<64><<<aggGrid, 256, 0, stream>>>(x16, offsets, csr, aggbuf);
    gemm_mfma<64><<<gemmGrid, 256, 0, stream>>>(aggbuf, x16, Wt0, bl0, bufB);
    // layer 1
    aggregate_bf16<128><<<aggGrid, 256, 0, stream>>>(bufB, offsets, csr, aggbuf);
    gemm_mfma<128><<<gemmGrid, 256, 0, stream>>>(aggbuf, bufB, Wt1, bl1, bufC);
    // layer 2
    aggregate_bf16<128><<<aggGrid, 256, 0, stream>>>(bufC, offsets, csr, aggbuf);
    gemm_mfma<128><<<gemmGrid, 256, 0, stream>>>(aggbuf, bufC, Wt2, bl2, bufB);

    pool_ln_decode<<<N_GRAPHS, 128, 0, stream>>>(bufB, batch, ln_g, ln_b, Wd, bd, out);
}

// Round 5
// 424.362 us; speedup vs baseline: 1.4071x; 1.4071x over previous
//
#include <hip/hip_runtime.h>

#define N_NODES  100000
#define N_EDGES  1600000
#define N_GRAPHS 512
#define LN_EPS   1e-5f

#define NB    256          // dst buckets
#define NPB   391          // nodes per bucket (256*391 = 100096 >= N_NODES)
#define BCAP  8192         // pool capacity per bucket (avg 6250, +24 sigma safe)
#define PCHUNK 8192
#define PBLOCKS ((N_EDGES + PCHUNK - 1) / PCHUNK)   // 196

typedef unsigned short u16;
typedef unsigned int   u32;
typedef __attribute__((ext_vector_type(8))) short bf16x8;
typedef __attribute__((ext_vector_type(4))) float f32x4;

__device__ __forceinline__ float b2f(u16 v) {
    u32 u = ((u32)v) << 16;
    return __builtin_bit_cast(float, u);
}
__device__ __forceinline__ u16 f2b(float f) {
    u32 u = __builtin_bit_cast(u32, f);
    u32 r = (u + 0x7fffu + ((u >> 16) & 1u)) >> 16;  // RNE
    return (u16)r;
}

// ---------------- bucketed CSR build ----------------
// Pass 1: bin edges into 256 dst-buckets. Per-block LDS histogram + one global
// atomicAdd per (block,bucket) -> contiguous run per block -> single-CU line
// ownership (kills the 64B-line cross-XCD write amplification seen in r3/r4).

__global__ __launch_bounds__(256)
void partition_edges(const int* __restrict__ src, const int* __restrict__ dst,
                     int* __restrict__ bcnt, uint2* __restrict__ bpool) {
    __shared__ int hist[NB];
    __shared__ int gbase[NB];
    __shared__ int cur[NB];
    int t = threadIdx.x;
    int e0 = blockIdx.x * PCHUNK;
    int e1 = e0 + PCHUNK; if (e1 > N_EDGES) e1 = N_EDGES;

    hist[t] = 0;
    __syncthreads();
    for (int e = e0 + t; e < e1; e += 256)
        atomicAdd(&hist[dst[e] / NPB], 1);
    __syncthreads();
    int h = hist[t];
    gbase[t] = (h > 0) ? atomicAdd(&bcnt[t], h) : 0;
    cur[t] = 0;
    __syncthreads();
    for (int e = e0 + t; e < e1; e += 256) {
        int d = dst[e], s = src[e];
        int b = d / NPB;
        int p = atomicAdd(&cur[b], 1);
        bpool[(size_t)b * BCAP + gbase[b] + p] = make_uint2((u32)d, (u32)s);
    }
}

__global__ void scan_buckets(const int* __restrict__ bcnt, int* __restrict__ bbase,
                             int* __restrict__ offsets) {
    __shared__ int sh[NB];
    int t = threadIdx.x;
    int v = bcnt[t];
    sh[t] = v; __syncthreads();
    for (int off = 1; off < NB; off <<= 1) {
        int add = (t >= off) ? sh[t - off] : 0;
        __syncthreads();
        sh[t] += add;
        __syncthreads();
    }
    bbase[t] = sh[t] - v;                         // exclusive
    if (t == NB - 1) offsets[N_NODES] = sh[t];    // == N_EDGES
}

// Pass 2: per bucket -> local hist, local scan -> offsets; scatter into LDS csr
// image; coalesced dump. All scattered traffic stays in LDS.
__global__ __launch_bounds__(256)
void build_csr_bucket(const int* __restrict__ bcnt, const int* __restrict__ bbase,
                      const uint2* __restrict__ bpool,
                      int* __restrict__ offsets, int* __restrict__ csr) {
    __shared__ int sA[512];
    __shared__ int sB[512];
    __shared__ int csrL[BCAP];
    int b = blockIdx.x, t = threadIdx.x;
    int nlo = b * NPB;
    int NL = N_NODES - nlo; if (NL > NPB) NL = NPB;
    int count = bcnt[b], base = bbase[b];
    const uint2* pool = bpool + (size_t)b * BCAP;

    sA[t] = 0; sA[t + 256] = 0;
    __syncthreads();
    for (int i = t; i < count; i += 256)
        atomicAdd(&sA[(int)pool[i].x - nlo], 1);
    __syncthreads();
    int c0 = sA[t], c1 = sA[t + 256];

    // inclusive Hillis-Steele scan over 512 entries (ping-pong buffers)
    int* a = sA; int* c = sB;
    for (int off = 1; off < 512; off <<= 1) {
        c[t]       = a[t]       + ((t >= off)       ? a[t - off]       : 0);
        c[t + 256] = a[t + 256] + ((t + 256 >= off) ? a[t + 256 - off] : 0);
        __syncthreads();
        int* tmp = a; a = c; c = tmp;
    }
    int ex0 = a[t] - c0, ex1 = a[t + 256] - c1;   // exclusive
    if (t < NL)       offsets[nlo + t]       = base + ex0;
    if (t + 256 < NL) offsets[nlo + t + 256] = base + ex1;
    // cursors in the free buffer (c)
    c[t] = ex0; c[t + 256] = ex1;
    __syncthreads();
    for (int i = t; i < count; i += 256) {
        uint2 p = pool[i];
        int pos = atomicAdd(&c[(int)p.x - nlo], 1);
        csrL[pos] = (int)p.y;
    }
    __syncthreads();
    for (int i = t; i < count; i += 256)
        csr[base + i] = csrL[i];
}

// ---------------- dtype conversions ----------------

__global__ __launch_bounds__(256)
void conv_f32_bf16(const float* __restrict__ in, u16* __restrict__ out, int n4) {
    int i = blockIdx.x * 256 + threadIdx.x;
    if (i < n4) {
        float4 v = ((const float4*)in)[i];
        u32 lo = (u32)f2b(v.x) | ((u32)f2b(v.y) << 16);
        u32 hi = (u32)f2b(v.z) | ((u32)f2b(v.w) << 16);
        ((uint2*)out)[i] = make_uint2(lo, hi);
    }
}

// Wt[c][k] = bf16( k<K1 ? Wl[k][c] : Wr[k-K1][c] )
__global__ __launch_bounds__(256)
void conv_weights(const float* __restrict__ Wl, const float* __restrict__ Wr,
                  int K1, int KC, u16* __restrict__ Wt) {
    int idx = blockIdx.x * 256 + threadIdx.x;
    if (idx >= 128 * KC) return;
    int c = idx / KC, k = idx % KC;
    float v = (k < K1) ? Wl[k * 128 + c] : Wr[(k - K1) * 128 + c];
    Wt[idx] = f2b(v);
}

// ---------------- mean aggregation (bf16 gather via CSR) ----------------
// 32 lanes per node, 8 nodes per 256-thr block, 4-way edge unroll.

template<int F>
__global__ __launch_bounds__(256)
void aggregate_bf16(const u16* __restrict__ in, const int* __restrict__ offsets,
                    const int* __restrict__ csr, u16* __restrict__ out) {
    int grp = threadIdx.x >> 5;
    int sub = threadIdx.x & 31;
    int n = blockIdx.x * 8 + grp;     // grid 12500 * 8 == N_NODES exactly
    int o0 = offsets[n], o1 = offsets[n + 1];
    int d = o1 - o0;
    float inv = 1.0f / (float)(d > 1 ? d : 1);

    if (F == 128) {
        const uint2* base = (const uint2*)in;      // row stride 32 uint2
        float acc[4][4];
        #pragma unroll
        for (int j = 0; j < 4; j++)
            #pragma unroll
            for (int c = 0; c < 4; c++) acc[j][c] = 0.f;

        int o = o0;
        for (; o + 4 <= o1; o += 4) {
            int s0 = csr[o + 0], s1 = csr[o + 1], s2 = csr[o + 2], s3 = csr[o + 3];
            uint2 v0 = base[(size_t)s0 * 32 + sub];
            uint2 v1 = base[(size_t)s1 * 32 + sub];
            uint2 v2 = base[(size_t)s2 * 32 + sub];
            uint2 v3 = base[(size_t)s3 * 32 + sub];
            acc[0][0] += b2f((u16)(v0.x & 0xffffu)); acc[0][1] += b2f((u16)(v0.x >> 16));
            acc[0][2] += b2f((u16)(v0.y & 0xffffu)); acc[0][3] += b2f((u16)(v0.y >> 16));
            acc[1][0] += b2f((u16)(v1.x & 0xffffu)); acc[1][1] += b2f((u16)(v1.x >> 16));
            acc[1][2] += b2f((u16)(v1.y & 0xffffu)); acc[1][3] += b2f((u16)(v1.y >> 16));
            acc[2][0] += b2f((u16)(v2.x & 0xffffu)); acc[2][1] += b2f((u16)(v2.x >> 16));
            acc[2][2] += b2f((u16)(v2.y & 0xffffu)); acc[2][3] += b2f((u16)(v2.y >> 16));
            acc[3][0] += b2f((u16)(v3.x & 0xffffu)); acc[3][1] += b2f((u16)(v3.x >> 16));
            acc[3][2] += b2f((u16)(v3.y & 0xffffu)); acc[3][3] += b2f((u16)(v3.y >> 16));
        }
        for (; o < o1; o++) {
            int s = csr[o];
            uint2 v = base[(size_t)s * 32 + sub];
            acc[0][0] += b2f((u16)(v.x & 0xffffu)); acc[0][1] += b2f((u16)(v.x >> 16));
            acc[0][2] += b2f((u16)(v.y & 0xffffu)); acc[0][3] += b2f((u16)(v.y >> 16));
        }
        float r0 = ((acc[0][0] + acc[1][0]) + (acc[2][0] + acc[3][0])) * inv;
        float r1 = ((acc[0][1] + acc[1][1]) + (acc[2][1] + acc[3][1])) * inv;
        float r2 = ((acc[0][2] + acc[1][2]) + (acc[2][2] + acc[3][2])) * inv;
        float r3 = ((acc[0][3] + acc[1][3]) + (acc[2][3] + acc[3][3])) * inv;
        uint2 w;
        w.x = (u32)f2b(r0) | ((u32)f2b(r1) << 16);
        w.y = (u32)f2b(r2) | ((u32)f2b(r3) << 16);
        ((uint2*)out)[(size_t)n * 32 + sub] = w;
    } else {
        const u32* base = (const u32*)in;          // row stride 32 u32
        float acc[4][2];
        #pragma unroll
        for (int j = 0; j < 4; j++) { acc[j][0] = 0.f; acc[j][1] = 0.f; }

        int o = o0;
        for (; o + 4 <= o1; o += 4) {
            int s0 = csr[o + 0], s1 = csr[o + 1], s2 = csr[o + 2], s3 = csr[o + 3];
            u32 v0 = base[(size_t)s0 * 32 + sub];
            u32 v1 = base[(size_t)s1 * 32 + sub];
            u32 v2 = base[(size_t)s2 * 32 + sub];
            u32 v3 = base[(size_t)s3 * 32 + sub];
            acc[0][0] += b2f((u16)(v0 & 0xffffu)); acc[0][1] += b2f((u16)(v0 >> 16));
            acc[1][0] += b2f((u16)(v1 & 0xffffu)); acc[1][1] += b2f((u16)(v1 >> 16));
            acc[2][0] += b2f((u16)(v2 & 0xffffu)); acc[2][1] += b2f((u16)(v2 >> 16));
            acc[3][0] += b2f((u16)(v3 & 0xffffu)); acc[3][1] += b2f((u16)(v3 >> 16));
        }
        for (; o < o1; o++) {
            int s = csr[o];
            u32 v = base[(size_t)s * 32 + sub];
            acc[0][0] += b2f((u16)(v & 0xffffu)); acc[0][1] += b2f((u16)(v >> 16));
        }
        float r0 = ((acc[0][0] + acc[1][0]) + (acc[2][0] + acc[3][0])) * inv;
        float r1 = ((acc[0][1] + acc[1][1]) + (acc[2][1] + acc[3][1])) * inv;
        ((u32*)out)[(size_t)n * 32 + sub] = (u32)f2b(r0) | ((u32)f2b(r1) << 16);
    }
}

// ---------------- fused dual GEMM via MFMA ----------------

template<int KHALF>
__global__ __launch_bounds__(256)
void gemm_mfma(const u16* __restrict__ A1, const u16* __restrict__ A2,
               const u16* __restrict__ Wt, const float* __restrict__ bias,
               u16* __restrict__ out) {
    constexpr int KC  = 2 * KHALF;
    constexpr int NKS = KC / 32;

    int t = threadIdx.x;
    int lane = t & 63, w = t >> 6;
    int l15 = lane & 15, l4 = lane >> 4;
    int mbase = blockIdx.x * 64;

    bf16x8 bfr[2][NKS];
    #pragma unroll
    for (int ct = 0; ct < 2; ct++)
        #pragma unroll
        for (int ks = 0; ks < NKS; ks++) {
            int row = w * 32 + ct * 16 + l15;          // output col
            int kb  = ks * 32 + l4 * 8;
            bfr[ct][ks] = *reinterpret_cast<const bf16x8*>(Wt + row * KC + kb);
        }

    f32x4 acc[4][2];
    #pragma unroll
    for (int i = 0; i < 4; i++)
        #pragma unroll
        for (int j = 0; j < 2; j++)
            acc[i][j] = (f32x4){0.f, 0.f, 0.f, 0.f};

    const bf16x8 zfr = {0, 0, 0, 0, 0, 0, 0, 0};

    #pragma unroll
    for (int ks = 0; ks < NKS; ks++) {
        const u16* Ab = (ks < NKS / 2) ? A1 : A2;
        int kb = (ks < NKS / 2) ? (ks * 32 + l4 * 8) : ((ks - NKS / 2) * 32 + l4 * 8);
        bf16x8 afr[4];
        #pragma unroll
        for (int rt = 0; rt < 4; rt++) {
            int row = mbase + rt * 16 + l15;
            afr[rt] = (row < N_NODES)
                ? *reinterpret_cast<const bf16x8*>(Ab + (size_t)row * KHALF + kb)
                : zfr;
        }
        #pragma unroll
        for (int rt = 0; rt < 4; rt++)
            #pragma unroll
            for (int ct = 0; ct < 2; ct++)
                acc[rt][ct] = __builtin_amdgcn_mfma_f32_16x16x32_bf16(
                    afr[rt], bfr[ct][ks], acc[rt][ct], 0, 0, 0);
    }

    // epilogue: bias + relu, store bf16. C/D: col=lane&15, row=(lane>>4)*4+reg
    #pragma unroll
    for (int ct = 0; ct < 2; ct++) {
        int col = w * 32 + ct * 16 + l15;
        float bv = bias[col];
        #pragma unroll
        for (int rt = 0; rt < 4; rt++) {
            #pragma unroll
            for (int j = 0; j < 4; j++) {
                int row = mbase + rt * 16 + l4 * 4 + j;
                if (row < N_NODES) {
                    float v = fmaxf(acc[rt][ct][j] + bv, 0.f);
                    out[(size_t)row * 128 + col] = f2b(v);
                }
            }
        }
    }
}

// ---------------- pool + LayerNorm + decode ----------------

__global__ __launch_bounds__(128)
void pool_ln_decode(const u16* __restrict__ h, const int* __restrict__ batch,
                    const float* __restrict__ ln_g, const float* __restrict__ ln_b,
                    const float* __restrict__ Wd, const float* __restrict__ bd,
                    float* __restrict__ out) {
    __shared__ float red[128];
    __shared__ int bounds[2];
    int g = blockIdx.x, c = threadIdx.x;
    if (c < 2) {
        int target = g + c;
        int lo = 0, hi = N_NODES;
        while (lo < hi) {
            int mid = (lo + hi) >> 1;
            if (batch[mid] < target) lo = mid + 1; else hi = mid;
        }
        bounds[c] = lo;
    }
    __syncthreads();
    int start = bounds[0], end = bounds[1];

    float s = 0.f;
    for (int r = start; r < end; r++) s += b2f(h[(size_t)r * 128 + c]);

    red[c] = s; __syncthreads();
    for (int off = 64; off > 0; off >>= 1) {
        if (c < off) red[c] += red[c + off];
        __syncthreads();
    }
    float mu = red[0] * (1.0f / 128.f);
    __syncthreads();

    float d = s - mu;
    red[c] = d * d; __syncthreads();
    for (int off = 64; off > 0; off >>= 1) {
        if (c < off) red[c] += red[c + off];
        __syncthreads();
    }
    float var = red[0] * (1.0f / 128.f);
    __syncthreads();

    float gn = d * rsqrtf(var + LN_EPS) * ln_g[c] + ln_b[c];

    red[c] = gn * Wd[c * 2 + 0]; __syncthreads();
    for (int off = 64; off > 0; off >>= 1) {
        if (c < off) red[c] += red[c + off];
        __syncthreads();
    }
    float o0 = red[0];
    __syncthreads();

    red[c] = gn * Wd[c * 2 + 1]; __syncthreads();
    for (int off = 64; off > 0; off >>= 1) {
        if (c < off) red[c] += red[c + off];
        __syncthreads();
    }
    if (c == 0) {
        out[g * 2 + 0] = o0 + bd[0];
        out[g * 2 + 1] = red[0] + bd[1];
    }
}

// ---------------- host launcher ----------------

extern "C" void kernel_launch(void* const* d_in, const int* in_sizes, int n_in,
                              void* d_out, int out_size, void* d_ws, size_t ws_size,
                              hipStream_t stream) {
    (void)in_sizes; (void)n_in; (void)out_size; (void)ws_size;

    const float* x     = (const float*)d_in[0];
    const int*   ei    = (const int*)d_in[1];
    const int*   batch = (const int*)d_in[2];
    const float* Wl0 = (const float*)d_in[3];
    const float* bl0 = (const float*)d_in[4];
    const float* Wr0 = (const float*)d_in[5];
    const float* Wl1 = (const float*)d_in[6];
    const float* bl1 = (const float*)d_in[7];
    const float* Wr1 = (const float*)d_in[8];
    const float* Wl2 = (const float*)d_in[9];
    const float* bl2 = (const float*)d_in[10];
    const float* Wr2 = (const float*)d_in[11];
    const float* ln_g = (const float*)d_in[12];
    const float* ln_b = (const float*)d_in[13];
    const float* Wd  = (const float*)d_in[14];
    const float* bd  = (const float*)d_in[15];
    float* out = (float*)d_out;

    const int* src = ei;
    const int* dst = ei + N_EDGES;

    // workspace layout (bytes)
    char* ws = (char*)d_ws;
    int*   csr     = (int*)(ws + 0);             //  6,400,000
    int*   offsets = (int*)(ws + 6400000);       //    400,128 (N+1 ints, padded)
    int*   bcnt    = (int*)(ws + 6800128);       //      1,024
    int*   bbase   = (int*)(ws + 6801152);       //      1,024
    uint2* bpool   = (uint2*)(ws + 6802176);     // 16,777,216 (256*8192*8)
    u16*   x16     = (u16*)(ws + 23579392);      // 12,800,000
    u16*   aggbuf  = (u16*)(ws + 36379392);      // 25,600,000
    u16*   bufB    = (u16*)(ws + 61979392);      // 25,600,000
    u16*   bufC    = (u16*)(ws + 87579392);      // 25,600,000
    u16*   Wt0     = (u16*)(ws + 113179392);     //     32,768
    u16*   Wt1     = (u16*)(ws + 113212160);     //     65,536
    u16*   Wt2     = (u16*)(ws + 113277696);     //     65,536
    // total: 113,343,232 bytes

    hipMemsetAsync(bcnt, 0, NB * sizeof(int), stream);

    partition_edges<<<PBLOCKS, 256, 0, stream>>>(src, dst, bcnt, bpool);
    scan_buckets<<<1, 256, 0, stream>>>(bcnt, bbase, offsets);
    build_csr_bucket<<<NB, 256, 0, stream>>>(bcnt, bbase, bpool, offsets, csr);

    // conversions
    conv_f32_bf16<<<(N_NODES * 64 / 4 + 255) / 256, 256, 0, stream>>>(x, x16, N_NODES * 64 / 4);
    conv_weights<<<(128 * 128 + 255) / 256, 256, 0, stream>>>(Wl0, Wr0, 64, 128, Wt0);
    conv_weights<<<(128 * 256 + 255) / 256, 256, 0, stream>>>(Wl1, Wr1, 128, 256, Wt1);
    conv_weights<<<(128 * 256 + 255) / 256, 256, 0, stream>>>(Wl2, Wr2, 128, 256, Wt2);

    const int aggGrid  = N_NODES / 8;               // 12500 (exact)
    const int gemmGrid = (N_NODES + 63) / 64;       // 1563

    // layer 0
    aggregate_bf16<64><<<aggGrid, 256, 0, stream>>>(x16, offsets, csr, aggbuf);
    gemm_mfma<64><<<gemmGrid, 256, 0, stream>>>(aggbuf, x16, Wt0, bl0, bufB);
    // layer 1
    aggregate_bf16<128><<<aggGrid, 256, 0, stream>>>(bufB, offsets, csr, aggbuf);
    gemm_mfma<128><<<gemmGrid, 256, 0, stream>>>(aggbuf, bufB, Wt1, bl1, bufC);
    // layer 2
    aggregate_bf16<128><<<aggGrid, 256, 0, stream>>>(bufC, offsets, csr, aggbuf);
    gemm_mfma<128><<<gemmGrid, 256, 0, stream>>>(aggbuf, bufC, Wt2, bl2, bufB);

    pool_ln_decode<<<N_GRAPHS, 128, 0, stream>>>(bufB, batch, ln_g, ln_b, Wd, bd, out);
}

// Round 6
// 375.396 us; speedup vs baseline: 1.5906x; 1.1304x over previous
//
#include <hip/hip_runtime.h>

#define N_NODES  100000
#define N_EDGES  1600000
#define N_GRAPHS 512
#define LN_EPS   1e-5f

#define NB    256          // dst buckets
#define NPB   391          // nodes per bucket (256*391 = 100096 >= N_NODES)
#define BCAP  8192         // pool capacity per bucket
#define PCHUNK 8192
#define PBLOCKS ((N_EDGES + PCHUNK - 1) / PCHUNK)   // 196
#define POOL_CHUNK 64
#define POOL_BLOCKS ((N_NODES + POOL_CHUNK - 1) / POOL_CHUNK)  // 1563

typedef unsigned short u16;
typedef unsigned int   u32;
typedef __attribute__((ext_vector_type(8))) short bf16x8;
typedef __attribute__((ext_vector_type(4))) float f32x4;

__device__ __forceinline__ float b2f(u16 v) {
    u32 u = ((u32)v) << 16;
    return __builtin_bit_cast(float, u);
}
__device__ __forceinline__ u16 f2b(float f) {
    u32 u = __builtin_bit_cast(u32, f);
    u32 r = (u + 0x7fffu + ((u >> 16) & 1u)) >> 16;  // RNE
    return (u16)r;
}

// ---------------- bucketed CSR build ----------------

__global__ __launch_bounds__(256)
void partition_edges(const int* __restrict__ src, const int* __restrict__ dst,
                     int* __restrict__ bcnt, uint2* __restrict__ bpool) {
    __shared__ int hist[NB];
    __shared__ int gbase[NB];
    __shared__ int cur[NB];
    int t = threadIdx.x;
    int e0 = blockIdx.x * PCHUNK;
    int e1 = e0 + PCHUNK; if (e1 > N_EDGES) e1 = N_EDGES;

    hist[t] = 0;
    __syncthreads();
    for (int e = e0 + t; e < e1; e += 256)
        atomicAdd(&hist[dst[e] / NPB], 1);
    __syncthreads();
    int h = hist[t];
    gbase[t] = (h > 0) ? atomicAdd(&bcnt[t], h) : 0;
    cur[t] = 0;
    __syncthreads();
    for (int e = e0 + t; e < e1; e += 256) {
        int d = dst[e], s = src[e];
        int b = d / NPB;
        int p = atomicAdd(&cur[b], 1);
        bpool[(size_t)b * BCAP + gbase[b] + p] = make_uint2((u32)d, (u32)s);
    }
}

__global__ void scan_buckets(const int* __restrict__ bcnt, int* __restrict__ bbase,
                             int* __restrict__ offsets) {
    __shared__ int sh[NB];
    int t = threadIdx.x;
    int v = bcnt[t];
    sh[t] = v; __syncthreads();
    for (int off = 1; off < NB; off <<= 1) {
        int add = (t >= off) ? sh[t - off] : 0;
        __syncthreads();
        sh[t] += add;
        __syncthreads();
    }
    bbase[t] = sh[t] - v;                         // exclusive
    if (t == NB - 1) offsets[N_NODES] = sh[t];    // == N_EDGES
}

__global__ __launch_bounds__(256)
void build_csr_bucket(const int* __restrict__ bcnt, const int* __restrict__ bbase,
                      const uint2* __restrict__ bpool,
                      int* __restrict__ offsets, int* __restrict__ csr) {
    __shared__ int sA[512];
    __shared__ int sB[512];
    __shared__ int csrL[BCAP];
    int b = blockIdx.x, t = threadIdx.x;
    int nlo = b * NPB;
    int NL = N_NODES - nlo; if (NL > NPB) NL = NPB;
    int count = bcnt[b], base = bbase[b];
    const uint2* pool = bpool + (size_t)b * BCAP;

    sA[t] = 0; sA[t + 256] = 0;
    __syncthreads();
    for (int i = t; i < count; i += 256)
        atomicAdd(&sA[(int)pool[i].x - nlo], 1);
    __syncthreads();
    int c0 = sA[t], c1 = sA[t + 256];

    int* a = sA; int* c = sB;
    for (int off = 1; off < 512; off <<= 1) {
        c[t]       = a[t]       + ((t >= off)       ? a[t - off]       : 0);
        c[t + 256] = a[t + 256] + ((t + 256 >= off) ? a[t + 256 - off] : 0);
        __syncthreads();
        int* tmp = a; a = c; c = tmp;
    }
    int ex0 = a[t] - c0, ex1 = a[t + 256] - c1;   // exclusive
    if (t < NL)       offsets[nlo + t]       = base + ex0;
    if (t + 256 < NL) offsets[nlo + t + 256] = base + ex1;
    c[t] = ex0; c[t + 256] = ex1;
    __syncthreads();
    for (int i = t; i < count; i += 256) {
        uint2 p = pool[i];
        int pos = atomicAdd(&c[(int)p.x - nlo], 1);
        csrL[pos] = (int)p.y;
    }
    __syncthreads();
    for (int i = t; i < count; i += 256)
        csr[base + i] = csrL[i];
}

// ---------------- dtype conversions ----------------

__global__ __launch_bounds__(256)
void conv_f32_bf16(const float* __restrict__ in, u16* __restrict__ out, int n4) {
    int i = blockIdx.x * 256 + threadIdx.x;
    if (i < n4) {
        float4 v = ((const float4*)in)[i];
        u32 lo = (u32)f2b(v.x) | ((u32)f2b(v.y) << 16);
        u32 hi = (u32)f2b(v.z) | ((u32)f2b(v.w) << 16);
        ((uint2*)out)[i] = make_uint2(lo, hi);
    }
}

__global__ __launch_bounds__(256)
void conv_weights(const float* __restrict__ Wl, const float* __restrict__ Wr,
                  int K1, int KC, u16* __restrict__ Wt) {
    int idx = blockIdx.x * 256 + threadIdx.x;
    if (idx >= 128 * KC) return;
    int c = idx / KC, k = idx % KC;
    float v = (k < K1) ? Wl[k * 128 + c] : Wr[(k - K1) * 128 + c];
    Wt[idx] = f2b(v);
}

// ---------------- mean aggregation (bf16 gather via CSR) ----------------

template<int F>
__global__ __launch_bounds__(256)
void aggregate_bf16(const u16* __restrict__ in, const int* __restrict__ offsets,
                    const int* __restrict__ csr, u16* __restrict__ out) {
    int grp = threadIdx.x >> 5;
    int sub = threadIdx.x & 31;
    int n = blockIdx.x * 8 + grp;     // grid 12500 * 8 == N_NODES exactly
    int o0 = offsets[n], o1 = offsets[n + 1];
    int d = o1 - o0;
    float inv = 1.0f / (float)(d > 1 ? d : 1);

    if (F == 128) {
        const uint2* base = (const uint2*)in;      // row stride 32 uint2
        float acc[4][4];
        #pragma unroll
        for (int j = 0; j < 4; j++)
            #pragma unroll
            for (int c = 0; c < 4; c++) acc[j][c] = 0.f;

        int o = o0;
        for (; o + 4 <= o1; o += 4) {
            int s0 = csr[o + 0], s1 = csr[o + 1], s2 = csr[o + 2], s3 = csr[o + 3];
            uint2 v0 = base[(size_t)s0 * 32 + sub];
            uint2 v1 = base[(size_t)s1 * 32 + sub];
            uint2 v2 = base[(size_t)s2 * 32 + sub];
            uint2 v3 = base[(size_t)s3 * 32 + sub];
            acc[0][0] += b2f((u16)(v0.x & 0xffffu)); acc[0][1] += b2f((u16)(v0.x >> 16));
            acc[0][2] += b2f((u16)(v0.y & 0xffffu)); acc[0][3] += b2f((u16)(v0.y >> 16));
            acc[1][0] += b2f((u16)(v1.x & 0xffffu)); acc[1][1] += b2f((u16)(v1.x >> 16));
            acc[1][2] += b2f((u16)(v1.y & 0xffffu)); acc[1][3] += b2f((u16)(v1.y >> 16));
            acc[2][0] += b2f((u16)(v2.x & 0xffffu)); acc[2][1] += b2f((u16)(v2.x >> 16));
            acc[2][2] += b2f((u16)(v2.y & 0xffffu)); acc[2][3] += b2f((u16)(v2.y >> 16));
            acc[3][0] += b2f((u16)(v3.x & 0xffffu)); acc[3][1] += b2f((u16)(v3.x >> 16));
            acc[3][2] += b2f((u16)(v3.y & 0xffffu)); acc[3][3] += b2f((u16)(v3.y >> 16));
        }
        for (; o < o1; o++) {
            int s = csr[o];
            uint2 v = base[(size_t)s * 32 + sub];
            acc[0][0] += b2f((u16)(v.x & 0xffffu)); acc[0][1] += b2f((u16)(v.x >> 16));
            acc[0][2] += b2f((u16)(v.y & 0xffffu)); acc[0][3] += b2f((u16)(v.y >> 16));
        }
        float r0 = ((acc[0][0] + acc[1][0]) + (acc[2][0] + acc[3][0])) * inv;
        float r1 = ((acc[0][1] + acc[1][1]) + (acc[2][1] + acc[3][1])) * inv;
        float r2 = ((acc[0][2] + acc[1][2]) + (acc[2][2] + acc[3][2])) * inv;
        float r3 = ((acc[0][3] + acc[1][3]) + (acc[2][3] + acc[3][3])) * inv;
        uint2 w;
        w.x = (u32)f2b(r0) | ((u32)f2b(r1) << 16);
        w.y = (u32)f2b(r2) | ((u32)f2b(r3) << 16);
        ((uint2*)out)[(size_t)n * 32 + sub] = w;
    } else {
        const u32* base = (const u32*)in;          // row stride 32 u32
        float acc[4][2];
        #pragma unroll
        for (int j = 0; j < 4; j++) { acc[j][0] = 0.f; acc[j][1] = 0.f; }

        int o = o0;
        for (; o + 4 <= o1; o += 4) {
            int s0 = csr[o + 0], s1 = csr[o + 1], s2 = csr[o + 2], s3 = csr[o + 3];
            u32 v0 = base[(size_t)s0 * 32 + sub];
            u32 v1 = base[(size_t)s1 * 32 + sub];
            u32 v2 = base[(size_t)s2 * 32 + sub];
            u32 v3 = base[(size_t)s3 * 32 + sub];
            acc[0][0] += b2f((u16)(v0 & 0xffffu)); acc[0][1] += b2f((u16)(v0 >> 16));
            acc[1][0] += b2f((u16)(v1 & 0xffffu)); acc[1][1] += b2f((u16)(v1 >> 16));
            acc[2][0] += b2f((u16)(v2 & 0xffffu)); acc[2][1] += b2f((u16)(v2 >> 16));
            acc[3][0] += b2f((u16)(v3 & 0xffffu)); acc[3][1] += b2f((u16)(v3 >> 16));
        }
        for (; o < o1; o++) {
            int s = csr[o];
            u32 v = base[(size_t)s * 32 + sub];
            acc[0][0] += b2f((u16)(v & 0xffffu)); acc[0][1] += b2f((u16)(v >> 16));
        }
        float r0 = ((acc[0][0] + acc[1][0]) + (acc[2][0] + acc[3][0])) * inv;
        float r1 = ((acc[0][1] + acc[1][1]) + (acc[2][1] + acc[3][1])) * inv;
        ((u32*)out)[(size_t)n * 32 + sub] = (u32)f2b(r0) | ((u32)f2b(r1) << 16);
    }
}

// ---------------- fused dual GEMM via MFMA ----------------

template<int KHALF>
__global__ __launch_bounds__(256)
void gemm_mfma(const u16* __restrict__ A1, const u16* __restrict__ A2,
               const u16* __restrict__ Wt, const float* __restrict__ bias,
               u16* __restrict__ out) {
    constexpr int KC  = 2 * KHALF;
    constexpr int NKS = KC / 32;

    int t = threadIdx.x;
    int lane = t & 63, w = t >> 6;
    int l15 = lane & 15, l4 = lane >> 4;
    int mbase = blockIdx.x * 64;

    bf16x8 bfr[2][NKS];
    #pragma unroll
    for (int ct = 0; ct < 2; ct++)
        #pragma unroll
        for (int ks = 0; ks < NKS; ks++) {
            int row = w * 32 + ct * 16 + l15;          // output col
            int kb  = ks * 32 + l4 * 8;
            bfr[ct][ks] = *reinterpret_cast<const bf16x8*>(Wt + row * KC + kb);
        }

    f32x4 acc[4][2];
    #pragma unroll
    for (int i = 0; i < 4; i++)
        #pragma unroll
        for (int j = 0; j < 2; j++)
            acc[i][j] = (f32x4){0.f, 0.f, 0.f, 0.f};

    const bf16x8 zfr = {0, 0, 0, 0, 0, 0, 0, 0};

    #pragma unroll
    for (int ks = 0; ks < NKS; ks++) {
        const u16* Ab = (ks < NKS / 2) ? A1 : A2;
        int kb = (ks < NKS / 2) ? (ks * 32 + l4 * 8) : ((ks - NKS / 2) * 32 + l4 * 8);
        bf16x8 afr[4];
        #pragma unroll
        for (int rt = 0; rt < 4; rt++) {
            int row = mbase + rt * 16 + l15;
            afr[rt] = (row < N_NODES)
                ? *reinterpret_cast<const bf16x8*>(Ab + (size_t)row * KHALF + kb)
                : zfr;
        }
        #pragma unroll
        for (int rt = 0; rt < 4; rt++)
            #pragma unroll
            for (int ct = 0; ct < 2; ct++)
                acc[rt][ct] = __builtin_amdgcn_mfma_f32_16x16x32_bf16(
                    afr[rt], bfr[ct][ks], acc[rt][ct], 0, 0, 0);
    }

    // epilogue: bias + relu, store bf16. C/D: col=lane&15, row=(lane>>4)*4+reg
    #pragma unroll
    for (int ct = 0; ct < 2; ct++) {
        int col = w * 32 + ct * 16 + l15;
        float bv = bias[col];
        #pragma unroll
        for (int rt = 0; rt < 4; rt++) {
            #pragma unroll
            for (int j = 0; j < 4; j++) {
                int row = mbase + rt * 16 + l4 * 4 + j;
                if (row < N_NODES) {
                    float v = fmaxf(acc[rt][ct][j] + bv, 0.f);
                    out[(size_t)row * 128 + col] = f2b(v);
                }
            }
        }
    }
}

// ---------------- pooling (parallel partial sums) + LN/decode ----------------
// batch is sorted; each 128-thr block walks POOL_CHUNK contiguous nodes,
// flushes a per-channel running sum via fp32 atomicAdd only at graph
// boundaries. ~280K atomics into 256KB L2-resident gpool.

__global__ __launch_bounds__(128)
void pool_partial(const u16* __restrict__ h, const int* __restrict__ batch,
                  float* __restrict__ gpool) {
    int c = threadIdx.x;
    int n0 = blockIdx.x * POOL_CHUNK;
    int n1 = n0 + POOL_CHUNK; if (n1 > N_NODES) n1 = N_NODES;
    float run = 0.f;
    int curg = -1;
    for (int r = n0; r < n1; r++) {
        int gid = batch[r];
        if (gid != curg) {
            if (curg >= 0) atomicAdd(&gpool[curg * 128 + c], run);
            run = 0.f; curg = gid;
        }
        run += b2f(h[(size_t)r * 128 + c]);
    }
    if (curg >= 0) atomicAdd(&gpool[curg * 128 + c], run);
}

__global__ __launch_bounds__(64)
void ln_decode(const float* __restrict__ gpool,
               const float* __restrict__ ln_g, const float* __restrict__ ln_b,
               const float* __restrict__ Wd, const float* __restrict__ bd,
               float* __restrict__ out) {
    int g = blockIdx.x, lane = threadIdx.x;
    float v0 = gpool[g * 128 + lane];
    float v1 = gpool[g * 128 + 64 + lane];
    float s = v0 + v1;
    #pragma unroll
    for (int off = 32; off > 0; off >>= 1) s += __shfl_xor(s, off, 64);
    float mu = s * (1.0f / 128.f);
    float d0 = v0 - mu, d1 = v1 - mu;
    float q = d0 * d0 + d1 * d1;
    #pragma unroll
    for (int off = 32; off > 0; off >>= 1) q += __shfl_xor(q, off, 64);
    float rs = rsqrtf(q * (1.0f / 128.f) + LN_EPS);
    float gn0 = d0 * rs * ln_g[lane]      + ln_b[lane];
    float gn1 = d1 * rs * ln_g[64 + lane] + ln_b[64 + lane];
    float o0 = gn0 * Wd[lane * 2 + 0] + gn1 * Wd[(64 + lane) * 2 + 0];
    float o1 = gn0 * Wd[lane * 2 + 1] + gn1 * Wd[(64 + lane) * 2 + 1];
    #pragma unroll
    for (int off = 32; off > 0; off >>= 1) {
        o0 += __shfl_xor(o0, off, 64);
        o1 += __shfl_xor(o1, off, 64);
    }
    if (lane == 0) {
        out[g * 2 + 0] = o0 + bd[0];
        out[g * 2 + 1] = o1 + bd[1];
    }
}

// ---------------- host launcher ----------------

extern "C" void kernel_launch(void* const* d_in, const int* in_sizes, int n_in,
                              void* d_out, int out_size, void* d_ws, size_t ws_size,
                              hipStream_t stream) {
    (void)in_sizes; (void)n_in; (void)out_size; (void)ws_size;

    const float* x     = (const float*)d_in[0];
    const int*   ei    = (const int*)d_in[1];
    const int*   batch = (const int*)d_in[2];
    const float* Wl0 = (const float*)d_in[3];
    const float* bl0 = (const float*)d_in[4];
    const float* Wr0 = (const float*)d_in[5];
    const float* Wl1 = (const float*)d_in[6];
    const float* bl1 = (const float*)d_in[7];
    const float* Wr1 = (const float*)d_in[8];
    const float* Wl2 = (const float*)d_in[9];
    const float* bl2 = (const float*)d_in[10];
    const float* Wr2 = (const float*)d_in[11];
    const float* ln_g = (const float*)d_in[12];
    const float* ln_b = (const float*)d_in[13];
    const float* Wd  = (const float*)d_in[14];
    const float* bd  = (const float*)d_in[15];
    float* out = (float*)d_out;

    const int* src = ei;
    const int* dst = ei + N_EDGES;

    // workspace layout (bytes)
    char* ws = (char*)d_ws;
    int*   csr     = (int*)(ws + 0);             //  6,400,000
    int*   offsets = (int*)(ws + 6400000);       //    400,128
    int*   bcnt    = (int*)(ws + 6800128);       //      1,024
    int*   bbase   = (int*)(ws + 6801152);       //      1,024
    uint2* bpool   = (uint2*)(ws + 6802176);     // 16,777,216
    u16*   x16     = (u16*)(ws + 23579392);      // 12,800,000
    u16*   aggbuf  = (u16*)(ws + 36379392);      // 25,600,000
    u16*   bufB    = (u16*)(ws + 61979392);      // 25,600,000
    u16*   bufC    = (u16*)(ws + 87579392);      // 25,600,000
    u16*   Wt0     = (u16*)(ws + 113179392);     //     32,768
    u16*   Wt1     = (u16*)(ws + 113212160);     //     65,536
    u16*   Wt2     = (u16*)(ws + 113277696);     //     65,536
    float* gpool   = (float*)(ws + 113343232);   //    262,144
    // total: 113,605,376 bytes

    hipMemsetAsync(bcnt, 0, NB * sizeof(int), stream);
    hipMemsetAsync(gpool, 0, N_GRAPHS * 128 * sizeof(float), stream);

    partition_edges<<<PBLOCKS, 256, 0, stream>>>(src, dst, bcnt, bpool);
    scan_buckets<<<1, 256, 0, stream>>>(bcnt, bbase, offsets);
    build_csr_bucket<<<NB, 256, 0, stream>>>(bcnt, bbase, bpool, offsets, csr);

    // conversions
    conv_f32_bf16<<<(N_NODES * 64 / 4 + 255) / 256, 256, 0, stream>>>(x, x16, N_NODES * 64 / 4);
    conv_weights<<<(128 * 128 + 255) / 256, 256, 0, stream>>>(Wl0, Wr0, 64, 128, Wt0);
    conv_weights<<<(128 * 256 + 255) / 256, 256, 0, stream>>>(Wl1, Wr1, 128, 256, Wt1);
    conv_weights<<<(128 * 256 + 255) / 256, 256, 0, stream>>>(Wl2, Wr2, 128, 256, Wt2);

    const int aggGrid  = N_NODES / 8;               // 12500 (exact)
    const int gemmGrid = (N_NODES + 63) / 64;       // 1563

    // layer 0
    aggregate_bf16<64><<<aggGrid, 256, 0, stream>>>(x16, offsets, csr, aggbuf);
    gemm_mfma<64><<<gemmGrid, 256, 0, stream>>>(aggbuf, x16, Wt0, bl0, bufB);
    // layer 1
    aggregate_bf16<128><<<aggGrid, 256, 0, stream>>>(bufB, offsets, csr, aggbuf);
    gemm_mfma<128><<<gemmGrid, 256, 0, stream>>>(aggbuf, bufB, Wt1, bl1, bufC);
    // layer 2
    aggregate_bf16<128><<<aggGrid, 256, 0, stream>>>(bufC, offsets, csr, aggbuf);
    gemm_mfma<128><<<gemmGrid, 256, 0, stream>>>(aggbuf, bufC, Wt2, bl2, bufB);

    // pool + LN + decode
    pool_partial<<<POOL_BLOCKS, 128, 0, stream>>>(bufB, batch, gpool);
    ln_decode<<<N_GRAPHS, 64, 0, stream>>>(gpool, ln_g, ln_b, Wd, bd, out);
}